// Round 1
// 33355.667 us; speedup vs baseline: 2.8575x; 2.8575x over previous
//
#include <hip/hip_runtime.h>
#include <math.h>

// QLSTM persistent kernel v2.
// - 256 blocks x 512 threads (8 waves/CU), block owns hidden {2b, 2b+1}, all 4 gates
//   (8 weight rows x 1024, f32, LDS-resident, padded stride for conflict-free reads).
// - x pre-transposed ONCE into the `out` buffer as xT[t][k][b] (safe aliasing: out[t]
//   slab is consumed at step t, h(t) store into it is deferred to step t+1, after the
//   device barrier). h published transposed hbufT[j][b] -> ALL staging is linear
//   global_load_lds dwordx4 into comb[k][64] (no VALU, no LDS write conflicts).
// - chunk loop: double-buffered, counted s_waitcnt vmcnt(4) + raw s_barrier so the
//   next chunk's loads stay in flight across the barrier.
// - dot: register tile 2 rows x 4 batches x 8-way split-K; ds_read_b128 for comb
//   (4 batches) and weights (4 k) -> 6 LDS instr : 32 FMA.
// - device barrier: per-block flag release-stores + master(block 0) gathers + single
//   `go` release; polls are RELAXED agent loads (no per-poll buffer_inv), one ACQUIRE
//   at the end. Replaces 256 contended RMWs + acquire-poll invalidate storm.

#define SEQ    2048
#define BATCH  64
#define DIN    512
#define HID    512
#define KTOT   (DIN + HID)            // 1024
#define NBLK   256
#define NTHR   512
#define CHUNK  128
#define NCHUNK 8
#define WSROW  1028                   // padded weight row stride (floats): rows start 4 banks apart
#define BHF    (BATCH * HID)          // floats per out t-slab (32768)
#define CBF    (CHUNK * BATCH)        // floats per comb chunk (8192)

__device__ __forceinline__ float sigmoidf_(float x) {
    return 1.0f / (1.0f + expf(-x));
}

__device__ __forceinline__ void lds_load16(const float* gsrc, float* ldst) {
    // async global->LDS, 16B/lane; LDS dest is wave-uniform base + lane*16
    __builtin_amdgcn_global_load_lds(
        (const __attribute__((address_space(1))) void*)gsrc,
        (__attribute__((address_space(3))) void*)ldst, 16, 0, 0);
}

__launch_bounds__(NTHR, 1)
__global__ void qlstm_v2(
    const float* __restrict__ x,                       // [SEQ][BATCH][DIN]
    const float* __restrict__ Wf, const float* __restrict__ bf,
    const float* __restrict__ Wi, const float* __restrict__ bi,
    const float* __restrict__ Wg, const float* __restrict__ bg,
    const float* __restrict__ Wo, const float* __restrict__ bo,
    float* __restrict__ out,                           // [SEQ][BATCH][HID] ++ hx ++ cx
    unsigned* __restrict__ go,                         // single release word
    unsigned* __restrict__ flags,                      // [NBLK] arrive flags
    float* __restrict__ hbufT)                         // [2][HID][BATCH], zeroed
{
    __shared__ float Wl[8 * WSROW];                    // 32.9 KB
    __shared__ float combf[2][CBF];                    // 64 KB (chunk double buffer)
    __shared__ float part[NCHUNK][8][BATCH];           // 16 KB (split-K partials)
    __shared__ float gl[8 * BATCH];                    // 2 KB  (gate pre-activations)
    __shared__ float bias_l[8];

    const int tid  = threadIdx.x;
    const int bid  = blockIdx.x;
    const int lane = tid & 63;
    const int wave = tid >> 6;        // 0..7 : k-slice (16 k per chunk)
    const int rp   = (tid >> 4) & 3;  // row pair: rows rp and rp+4
    const int bq   = tid & 15;        // batch quad: batches 4*bq..4*bq+3
    const int j0   = bid * 2;

    // ---------------- one-time: weights + biases into LDS ----------------
    {
        const float* wsrcs[4] = { Wf, Wi, Wg, Wo };
        const float* bsrcs[4] = { bf, bi, bg, bo };
        for (int g = 0; g < 4; ++g) {
            const float* ws0 = wsrcs[g] + (size_t)(j0 + 0) * KTOT;
            const float* ws1 = wsrcs[g] + (size_t)(j0 + 1) * KTOT;
            for (int i = tid; i < KTOT; i += NTHR) {
                Wl[(g * 2 + 0) * WSROW + i] = ws0[i];
                Wl[(g * 2 + 1) * WSROW + i] = ws1[i];
            }
            if (tid == 0) {
                bias_l[g * 2 + 0] = bsrcs[g][j0 + 0];
                bias_l[g * 2 + 1] = bsrcs[g][j0 + 1];
            }
        }
    }

    // ---------------- pre-pass: x[t][b][k] -> out[t] slab as xT[t][k][b] ----------------
    // Each block transposes 8 t-slices via an LDS bounce tile (one-time cost).
    {
        float* tile = &combf[0][0];                    // needs 128*65=8320 floats (<16384)
        const float4* x4 = (const float4*)x;
        for (int tt = 0; tt < 8; ++tt) {
            const int t = bid * 8 + tt;
            for (int ck = 0; ck < 4; ++ck) {
                __syncthreads();                       // tile reusable
                #pragma unroll
                for (int it = 0; it < 4; ++it) {
                    int idx = it * NTHR + tid;         // 0..2047
                    int b = idx >> 5, q = idx & 31;
                    float4 v = x4[(size_t)(t * BATCH + b) * (DIN / 4) + ck * 32 + q];
                    tile[(4 * q + 0) * 65 + b] = v.x;
                    tile[(4 * q + 1) * 65 + b] = v.y;
                    tile[(4 * q + 2) * 65 + b] = v.z;
                    tile[(4 * q + 3) * 65 + b] = v.w;
                }
                __syncthreads();
                #pragma unroll
                for (int it = 0; it < 4; ++it) {
                    int fl = it * (NTHR * 4) + tid * 4;   // 0..8188
                    int kl = fl >> 6, b0 = fl & 63;
                    float4 o;
                    o.x = tile[kl * 65 + b0 + 0];
                    o.y = tile[kl * 65 + b0 + 1];
                    o.z = tile[kl * 65 + b0 + 2];
                    o.w = tile[kl * 65 + b0 + 3];
                    *(float4*)&out[(size_t)t * BHF + ck * CBF + fl] = o;
                }
            }
        }
    }

    // ---------------- device-wide barrier (flags + master release) ----------------
    auto gridbar = [&](unsigned target) {
        __syncthreads();   // all waves' global stores drained (compiler vmcnt(0) here)
        if (tid == 0)
            __hip_atomic_store(&flags[bid], target, __ATOMIC_RELEASE, __HIP_MEMORY_SCOPE_AGENT);
        if (bid == 0 && tid < 64) {
            const int i0 = tid * 4;
            for (;;) {
                unsigned a = __hip_atomic_load(&flags[i0 + 0], __ATOMIC_RELAXED, __HIP_MEMORY_SCOPE_AGENT);
                unsigned b = __hip_atomic_load(&flags[i0 + 1], __ATOMIC_RELAXED, __HIP_MEMORY_SCOPE_AGENT);
                unsigned c = __hip_atomic_load(&flags[i0 + 2], __ATOMIC_RELAXED, __HIP_MEMORY_SCOPE_AGENT);
                unsigned d = __hip_atomic_load(&flags[i0 + 3], __ATOMIC_RELAXED, __HIP_MEMORY_SCOPE_AGENT);
                if (a >= target && b >= target && c >= target && d >= target) break;
                __builtin_amdgcn_s_sleep(1);
            }
            if (tid == 0)
                __hip_atomic_store(go, target, __ATOMIC_RELEASE, __HIP_MEMORY_SCOPE_AGENT);
        }
        if (tid == 0) {
            while (__hip_atomic_load(go, __ATOMIC_RELAXED, __HIP_MEMORY_SCOPE_AGENT) < target)
                __builtin_amdgcn_s_sleep(2);
            (void)__hip_atomic_load(go, __ATOMIC_ACQUIRE, __HIP_MEMORY_SCOPE_AGENT);  // one inv
        }
        __syncthreads();
    };

    gridbar(1u);   // pre-pass + weight load complete everywhere

    // ---------------- recurrence ----------------
    float c_reg = 0.0f, h_keep = 0.0f;
    const int b = lane;               // batch index for gate threads (tid < 128)

    #pragma unroll 1
    for (int t = 0; t < SEQ; ++t) {
        const int cur = t & 1;
        const float* xT_t = out   + (size_t)t * BHF;
        const float* hT   = hbufT + (size_t)cur * (HID * BATCH);

        // deferred store of h(t-1) into out[t-1] (slab is dead after the barrier)
        if (t > 0 && tid < 2 * BATCH)
            out[(size_t)(t - 1) * BHF + (size_t)b * HID + (j0 + wave)] = h_keep;

        // issue chunk 0 (x part): 4 x 1KB per wave
        #pragma unroll
        for (int i = 0; i < 4; ++i) {
            const int off = (wave * 4 + i) * 256;
            lds_load16(xT_t + off + lane * 4, &combf[0][off]);
        }

        float4 acc0, acc1;
        {
            const float bz0 = (wave == 0) ? bias_l[rp]     : 0.0f;
            const float bz1 = (wave == 0) ? bias_l[rp + 4] : 0.0f;
            acc0 = make_float4(bz0, bz0, bz0, bz0);
            acc1 = make_float4(bz1, bz1, bz1, bz1);
        }

        #pragma unroll
        for (int c = 0; c < NCHUNK; ++c) {
            if (c + 1 < NCHUNK) {
                // issue chunk c+1 into the other buffer (its old contents, chunk c-1,
                // were fully consumed before the trailing barrier of iter c-1)
                const float* src = (c + 1 < 4) ? (xT_t + (c + 1) * CBF)
                                               : (hT + (c + 1 - 4) * CBF);
                float* dst = &combf[(c + 1) & 1][0];
                #pragma unroll
                for (int i = 0; i < 4; ++i) {
                    const int off = (wave * 4 + i) * 256;
                    lds_load16(src + off + lane * 4, dst + off);
                }
                // drain chunk c's 4 loads (oldest), keep chunk c+1's 4 in flight
                asm volatile("s_waitcnt vmcnt(4)" ::: "memory");
            } else {
                asm volatile("s_waitcnt vmcnt(0)" ::: "memory");
            }
            __builtin_amdgcn_s_barrier();     // raw: no vmcnt(0) auto-drain
            asm volatile("" ::: "memory");

            // compute chunk c: this thread's 16-k slice, 2 rows x 4 batches
            const float* cbp = &combf[c & 1][(wave * 16) * BATCH + bq * 4];
            const float* w0p = &Wl[rp * WSROW + c * CHUNK + wave * 16];
            const float* w1p = &Wl[(rp + 4) * WSROW + c * CHUNK + wave * 16];
            #pragma unroll
            for (int kk = 0; kk < 16; kk += 4) {
                float4 w0 = *(const float4*)(w0p + kk);
                float4 w1 = *(const float4*)(w1p + kk);
                const float w0a[4] = { w0.x, w0.y, w0.z, w0.w };
                const float w1a[4] = { w1.x, w1.y, w1.z, w1.w };
                #pragma unroll
                for (int i = 0; i < 4; ++i) {
                    float4 cv = *(const float4*)(cbp + (kk + i) * BATCH);
                    acc0.x = fmaf(w0a[i], cv.x, acc0.x);
                    acc0.y = fmaf(w0a[i], cv.y, acc0.y);
                    acc0.z = fmaf(w0a[i], cv.z, acc0.z);
                    acc0.w = fmaf(w0a[i], cv.w, acc0.w);
                    acc1.x = fmaf(w1a[i], cv.x, acc1.x);
                    acc1.y = fmaf(w1a[i], cv.y, acc1.y);
                    acc1.z = fmaf(w1a[i], cv.z, acc1.z);
                    acc1.w = fmaf(w1a[i], cv.w, acc1.w);
                }
            }
            asm volatile("" ::: "memory");
            __builtin_amdgcn_s_barrier();     // compute done -> next iter may overwrite buf
        }

        // split-K partials -> LDS, reduce, gates
        *(float4*)&part[wave][rp][bq * 4]     = acc0;
        *(float4*)&part[wave][rp + 4][bq * 4] = acc1;
        __syncthreads();
        {
            const int row = wave;             // tid>>6
            const int bb  = lane;
            float s = part[0][row][bb] + part[1][row][bb] + part[2][row][bb] + part[3][row][bb]
                    + part[4][row][bb] + part[5][row][bb] + part[6][row][bb] + part[7][row][bb];
            gl[row * BATCH + bb] = s;
        }
        __syncthreads();
        if (tid < 2 * BATCH) {                // wave in {0,1} == jj
            const int jj = wave;
            float fv = sigmoidf_(gl[(0 + jj) * BATCH + b]);
            float iv = sigmoidf_(gl[(2 + jj) * BATCH + b]);
            float gv = tanhf    (gl[(4 + jj) * BATCH + b]);
            float ov = sigmoidf_(gl[(6 + jj) * BATCH + b]);
            c_reg  = fv * c_reg + iv * gv;
            h_keep = ov * tanhf(c_reg);
            // publish h transposed for next step's linear staging
            hbufT[(size_t)(1 - cur) * (HID * BATCH) + (size_t)(j0 + jj) * BATCH + b] = h_keep;
        }

        // barrier every step (incl. last: protects xT[SEQ-1] readers from epilogue stores)
        gridbar((unsigned)(t + 2));
    }

    // ---------------- epilogue ----------------
    if (tid < 2 * BATCH) {
        const int jj = wave;
        out[(size_t)(SEQ - 1) * BHF + (size_t)b * HID + (j0 + jj)] = h_keep;
        const size_t ob = (size_t)SEQ * BHF;
        out[ob +       (size_t)b * HID + (j0 + jj)] = h_keep;
        out[ob + BHF + (size_t)b * HID + (j0 + jj)] = c_reg;
    }
}

extern "C" void kernel_launch(void* const* d_in, const int* in_sizes, int n_in,
                              void* d_out, int out_size, void* d_ws, size_t ws_size,
                              hipStream_t stream) {
    const float* x  = (const float*)d_in[0];
    const float* Wf = (const float*)d_in[1];
    const float* bf = (const float*)d_in[2];
    const float* Wi = (const float*)d_in[3];
    const float* bi = (const float*)d_in[4];
    const float* Wg = (const float*)d_in[5];
    const float* bg = (const float*)d_in[6];
    const float* Wo = (const float*)d_in[7];
    const float* bo = (const float*)d_in[8];
    float* out = (float*)d_out;

    unsigned* go    = (unsigned*)d_ws;
    unsigned* flags = (unsigned*)((char*)d_ws + 256);
    float* hbufT    = (float*)((char*)d_ws + 4096);

    // zero barrier state + transposed h double-buffer (ws poisoned each call)
    hipMemsetAsync(d_ws, 0, 4096 + 2 * HID * BATCH * sizeof(float), stream);

    qlstm_v2<<<NBLK, NTHR, 0, stream>>>(
        x, Wf, bf, Wi, bi, Wg, bg, Wo, bo, out, go, flags, hbufT);
}

// Round 2
// 25418.167 us; speedup vs baseline: 3.7498x; 1.3123x over previous
//
#include <hip/hip_runtime.h>
#include <math.h>

// QLSTM persistent kernel v3.
// 256 blocks x 512 threads (8 waves). Block owns hidden {2b,2b+1} = 8 gate rows.
// - Weights in VGPRs: thread tile 8 rows x 8 batch x 16 k (k = c*128 + lane*2 + q).
//   wreg[8][16] = 128 VGPR, acc[64]. Zero weight LDS traffic.
// - comb LDS slots [4][64 b][128 k]; wave w stages AND reads only batches w*8..w*8+8
//   -> no cross-wave barriers in the chunk loop; per-wave counted vmcnt only.
// - x staged straight from native x[t][b][k] via global_load_lds (L2-cached, aux=0);
//   chunks 0-3 for step t+1 are issued BEFORE the grid barrier (stay in flight).
// - h staged via inline-asm global_load_dwordx4 sc0 sc1 (bypass L1/L2 -> LLC-coherent)
//   + ds_write; h stores are global_store_dword sc0 sc1. NO acquire/buffer_inv ever:
//   per-XCD L2 is never invalidated, so x hits L2 every step.
// - split-K reduce: in-register butterfly (cndmask select + __shfl_xor), static reg
//   indices; lane l of wave w ends with pre-activation for (row=l>>3, b=w*8+(l&7)).
// - grid barrier: per-block relaxed flag stores + block0 wave-lockstep gather + go.

#define SEQ    2048
#define BATCH  64
#define DIN    512
#define HID    512
#define NBLK   256
#define NTHR   512
#define BHF    (BATCH * HID)          // 32768 floats per out t-slab

__device__ __forceinline__ float sigmoidf_(float x) { return 1.0f / (1.0f + expf(-x)); }

__device__ __forceinline__ void lds_load16(const float* gsrc, float* ldst) {
    __builtin_amdgcn_global_load_lds(
        (const __attribute__((address_space(1))) void*)gsrc,
        (__attribute__((address_space(3))) void*)ldst, 16, 0, 0);
}

__device__ __forceinline__ float4 gload4_cc(const float* p) {   // coherent: bypass L1+L2
    float4 v;
    asm volatile("global_load_dwordx4 %0, %1, off sc0 sc1"
                 : "=&v"(v) : "v"(p) : "memory");
    return v;
}
__device__ __forceinline__ void gstore_cc(float* p, float v) {  // write-through to LLC
    asm volatile("global_store_dword %0, %1, off sc0 sc1"
                 :: "v"(p), "v"(v) : "memory");
}
#define VMW(n) asm volatile("s_waitcnt vmcnt(" #n ")" ::: "memory")

__launch_bounds__(NTHR, 1)
__global__ void qlstm_v3(
    const float* __restrict__ x,                       // [SEQ][BATCH][DIN]
    const float* __restrict__ Wf, const float* __restrict__ bf,
    const float* __restrict__ Wi, const float* __restrict__ bi,
    const float* __restrict__ Wg, const float* __restrict__ bg,
    const float* __restrict__ Wo, const float* __restrict__ bo,
    float* __restrict__ out,                           // [SEQ][BATCH][HID] ++ hx ++ cx
    unsigned* __restrict__ go,
    unsigned* __restrict__ flags,                      // [NBLK]
    const float* __restrict__ zbuf)                    // [BATCH][HID] zeros (t=0 h)
{
    __shared__ float comb[4][8192];                    // 128 KB: slot[64 b][128 k]
    __shared__ float gl[8][68];                        // padded: conflict-free
    __shared__ float bias_l[8];

    const int tid  = threadIdx.x;
    const int bid  = blockIdx.x;
    const int lane = tid & 63;
    const int w    = tid >> 6;        // wave = batch group (batches w*8 .. w*8+8)
    const int hl   = lane >> 5;       // which of 2 batches within a 1KB stage instr
    const int klo  = (lane & 31) * 4; // k offset within chunk for staging
    const int j0   = bid * 2;

    // ---------- one-time: weights -> VGPR, biases -> LDS ----------
    float wreg[128];                  // wreg[r*16 + c*2 + q] = W_r[c*128 + lane*2 + q]
    {
        const float* wsrcs[4] = { Wf, Wi, Wg, Wo };
        #pragma unroll
        for (int g = 0; g < 4; ++g)
            #pragma unroll
            for (int jj = 0; jj < 2; ++jj) {
                const float* wp = wsrcs[g] + (size_t)(j0 + jj) * 1024;
                #pragma unroll
                for (int c = 0; c < 8; ++c) {
                    float2 v = *(const float2*)(wp + c * 128 + lane * 2);
                    wreg[(g * 2 + jj) * 16 + c * 2]     = v.x;
                    wreg[(g * 2 + jj) * 16 + c * 2 + 1] = v.y;
                }
            }
        if (tid < 8) {
            const float* bsrcs[4] = { bf, bi, bg, bo };
            bias_l[tid] = bsrcs[tid >> 1][j0 + (tid & 1)];
        }
    }
    __syncthreads();   // drains weight loads (vmcnt clean before pipelined staging)

// stage x chunk cc of timestep tt into slot ss (wave-private region, linear LDS)
#define STAGE_X(tt, cc, ss) {                                                      \
    const float* xs_ = x + ((size_t)(tt) * BATCH + w * 8) * DIN + (cc) * 128 + klo; \
    _Pragma("unroll")                                                              \
    for (int i_ = 0; i_ < 4; ++i_)                                                 \
        lds_load16(xs_ + (i_ * 2 + hl) * DIN, &comb[ss][w * 1024 + i_ * 256]); }

#define ISSUE_H(cc, d0, d1, d2, d3) {                                              \
    const float* hs_ = hsrc + (size_t)(w * 8) * HID + ((cc) - 4) * 128 + klo;      \
    d0 = gload4_cc(hs_ + (0 * 2 + hl) * HID);                                      \
    d1 = gload4_cc(hs_ + (1 * 2 + hl) * HID);                                      \
    d2 = gload4_cc(hs_ + (2 * 2 + hl) * HID);                                      \
    d3 = gload4_cc(hs_ + (3 * 2 + hl) * HID); }

#define WRITE_H(ss, d0, d1, d2, d3) {                                              \
    *(float4*)&comb[ss][w * 1024 + 0 * 256 + lane * 4] = d0;                       \
    *(float4*)&comb[ss][w * 1024 + 1 * 256 + lane * 4] = d1;                       \
    *(float4*)&comb[ss][w * 1024 + 2 * 256 + lane * 4] = d2;                       \
    *(float4*)&comb[ss][w * 1024 + 3 * 256 + lane * 4] = d3; }

// compute chunk cc from slot ss: 8 ds_read_b64 (conflict-free) feed 128 FMAs
#define CHUNK_FMA(cc, ss) {                                                        \
    _Pragma("unroll")                                                              \
    for (int j_ = 0; j_ < 8; ++j_) {                                               \
        float2 cv_ = *(const float2*)&comb[ss][w * 1024 + j_ * 128 + lane * 2];    \
        _Pragma("unroll")                                                          \
        for (int r_ = 0; r_ < 8; ++r_) {                                           \
            acc[r_ * 8 + j_] = fmaf(cv_.x, wreg[r_ * 16 + (cc) * 2],     acc[r_ * 8 + j_]); \
            acc[r_ * 8 + j_] = fmaf(cv_.y, wreg[r_ * 16 + (cc) * 2 + 1], acc[r_ * 8 + j_]); \
        } } }

    // prologue: stage x chunks of step 0 (no cross-block dependency at t=0)
    STAGE_X(0, 0, 0); STAGE_X(0, 1, 1); STAGE_X(0, 2, 2); STAGE_X(0, 3, 3);

    float c_reg = 0.0f, h_keep = 0.0f;

    #pragma unroll 1
    for (int t = 0; t < SEQ; ++t) {
        const float* hsrc = (t == 0) ? zbuf : out + (size_t)(t - 1) * BHF;
        float4 ha0, ha1, ha2, ha3, hb0, hb1, hb2, hb3;
        ISSUE_H(4, ha0, ha1, ha2, ha3);      // h chunks depth-2 in flight
        ISSUE_H(5, hb0, hb1, hb2, hb3);

        float acc[64];
        #pragma unroll
        for (int v = 0; v < 64; ++v) acc[v] = 0.0f;

        // x chunks (prefetched across the barrier): counted waits, oldest-first
        VMW(20); CHUNK_FMA(0, 0);
        VMW(16); CHUNK_FMA(1, 1);
        VMW(12); CHUNK_FMA(2, 2);
        VMW(8);  CHUNK_FMA(3, 3);
        // h chunks: reg->LDS (wave-private), reuse reg sets
        VMW(4);  WRITE_H(0, ha0, ha1, ha2, ha3); ISSUE_H(6, ha0, ha1, ha2, ha3);
                 CHUNK_FMA(4, 0);
        VMW(4);  WRITE_H(1, hb0, hb1, hb2, hb3); ISSUE_H(7, hb0, hb1, hb2, hb3);
                 CHUNK_FMA(5, 1);
        VMW(4);  WRITE_H(2, ha0, ha1, ha2, ha3); CHUNK_FMA(6, 2);
        VMW(0);  WRITE_H(3, hb0, hb1, hb2, hb3); CHUNK_FMA(7, 3);

        // ---- split-K butterfly reduce: after stage m, kept value's bit m == lane's ----
        #pragma unroll
        for (int i = 0; i < 32; ++i) {
            float E = (lane & 32) ? acc[32 + i] : acc[i];
            float F = (lane & 32) ? acc[i]      : acc[32 + i];
            acc[i] = E + __shfl_xor(F, 32, 64);
        }
        #pragma unroll
        for (int i = 0; i < 16; ++i) {
            float E = (lane & 16) ? acc[16 + i] : acc[i];
            float F = (lane & 16) ? acc[i]      : acc[16 + i];
            acc[i] = E + __shfl_xor(F, 16, 64);
        }
        #pragma unroll
        for (int i = 0; i < 8; ++i) {
            float E = (lane & 8) ? acc[8 + i] : acc[i];
            float F = (lane & 8) ? acc[i]     : acc[8 + i];
            acc[i] = E + __shfl_xor(F, 8, 64);
        }
        #pragma unroll
        for (int i = 0; i < 4; ++i) {
            float E = (lane & 4) ? acc[4 + i] : acc[i];
            float F = (lane & 4) ? acc[i]     : acc[4 + i];
            acc[i] = E + __shfl_xor(F, 4, 64);
        }
        #pragma unroll
        for (int i = 0; i < 2; ++i) {
            float E = (lane & 2) ? acc[2 + i] : acc[i];
            float F = (lane & 2) ? acc[i]     : acc[2 + i];
            acc[i] = E + __shfl_xor(F, 2, 64);
        }
        {
            float E = (lane & 1) ? acc[1] : acc[0];
            float F = (lane & 1) ? acc[0] : acc[1];
            acc[0] = E + __shfl_xor(F, 1, 64);
        }
        // lane holds pre-activation for (row = lane>>3, b = w*8 + (lane&7))
        gl[lane >> 3][w * 8 + (lane & 7)] = acc[0] + bias_l[lane >> 3];
        __syncthreads();   // vmcnt already 0 here; no prefetch loss

        if (tid < 128) {   // waves 0,1: gate nonlinearities for (jj = w, b = lane)
            const int jj = w;
            const int b  = lane;
            float fv = sigmoidf_(gl[0 + jj][b]);
            float iv = sigmoidf_(gl[2 + jj][b]);
            float gv = tanhf    (gl[4 + jj][b]);
            float ov = sigmoidf_(gl[6 + jj][b]);
            c_reg  = fv * c_reg + iv * gv;
            h_keep = ov * tanhf(c_reg);
            gstore_cc(out + (size_t)t * BHF + (size_t)b * HID + (j0 + jj), h_keep);
        }

        if (t < SEQ - 1) {
            // prefetch next step's x chunks; they stay in flight across the barrier
            STAGE_X(t + 1, 0, 0); STAGE_X(t + 1, 1, 1);
            STAGE_X(t + 1, 2, 2); STAGE_X(t + 1, 3, 3);
            if (tid < 128) VMW(16);          // h-store (oldest) drained; 16 loads flying
            __builtin_amdgcn_s_barrier();    // raw: no vmcnt(0) drain
            const unsigned target = (unsigned)(t + 1);
            if (tid == 0)
                __hip_atomic_store(&flags[bid], target, __ATOMIC_RELAXED,
                                   __HIP_MEMORY_SCOPE_AGENT);
            if (bid == 0 && tid < 64) {      // wave-lockstep gather of all 256 flags
                const int i0 = tid * 4;
                for (;;) {
                    unsigned a = __hip_atomic_load(&flags[i0 + 0], __ATOMIC_RELAXED, __HIP_MEMORY_SCOPE_AGENT);
                    unsigned b = __hip_atomic_load(&flags[i0 + 1], __ATOMIC_RELAXED, __HIP_MEMORY_SCOPE_AGENT);
                    unsigned c = __hip_atomic_load(&flags[i0 + 2], __ATOMIC_RELAXED, __HIP_MEMORY_SCOPE_AGENT);
                    unsigned d = __hip_atomic_load(&flags[i0 + 3], __ATOMIC_RELAXED, __HIP_MEMORY_SCOPE_AGENT);
                    if (a >= target && b >= target && c >= target && d >= target) break;
                    __builtin_amdgcn_s_sleep(1);
                }
                if (tid == 0)
                    __hip_atomic_store(go, target, __ATOMIC_RELAXED,
                                       __HIP_MEMORY_SCOPE_AGENT);
            }
            if (tid == 0) {
                while (__hip_atomic_load(go, __ATOMIC_RELAXED,
                                         __HIP_MEMORY_SCOPE_AGENT) < target)
                    __builtin_amdgcn_s_sleep(1);
            }
            __builtin_amdgcn_s_barrier();
        }
    }

    // ---------------- epilogue: hx, cx ----------------
    if (tid < 128) {
        const int jj = w;
        const int b  = lane;
        const size_t ob = (size_t)SEQ * BHF;
        out[ob +       (size_t)b * HID + (j0 + jj)] = h_keep;
        out[ob + BHF + (size_t)b * HID + (j0 + jj)] = c_reg;
    }
}

extern "C" void kernel_launch(void* const* d_in, const int* in_sizes, int n_in,
                              void* d_out, int out_size, void* d_ws, size_t ws_size,
                              hipStream_t stream) {
    const float* x  = (const float*)d_in[0];
    const float* Wf = (const float*)d_in[1];
    const float* bf = (const float*)d_in[2];
    const float* Wi = (const float*)d_in[3];
    const float* bi = (const float*)d_in[4];
    const float* Wg = (const float*)d_in[5];
    const float* bg = (const float*)d_in[6];
    const float* Wo = (const float*)d_in[7];
    const float* bo = (const float*)d_in[8];
    float* out = (float*)d_out;

    unsigned* go    = (unsigned*)d_ws;
    unsigned* flags = (unsigned*)((char*)d_ws + 256);
    float*    zbuf  = (float*)((char*)d_ws + 4096);

    // zero go + flags + zbuf (ws is poisoned each call)
    hipMemsetAsync(d_ws, 0, 4096 + BATCH * HID * sizeof(float), stream);

    qlstm_v3<<<NBLK, NTHR, 0, stream>>>(
        x, Wf, bf, Wi, bi, Wg, bg, Wo, bo, out, go, flags, zbuf);
}